// Round 5
// baseline (2092.930 us; speedup 1.0000x reference)
//
#include <hip/hip_runtime.h>

#define BN 4096     // batch
#define DF 784
#define HALFF 392
#define HIDF 512
#define NBLK 20
#define KS1 448     // padded K for GEMM1 (392 -> 7*64)
#define KS2 512     // K for GEMM2 (8*64)
#define PP  848     // P pitch (halves)
#define YP  448     // Y1/Y2 pitch (halves)
#define NT1 7       // K-tiles gemm1
#define NT2 8       // K-tiles gemm2

typedef _Float16 f16;
typedef _Float16 half4v __attribute__((ext_vector_type(4)));
typedef _Float16 half8v __attribute__((ext_vector_type(8)));
typedef float    fx4    __attribute__((ext_vector_type(4)));
typedef int      ix4    __attribute__((ext_vector_type(4)));

// ---------------------------------------------------------------------------
// prep_k: fp32 weights [m][k][N] -> fp16 [m][n][KS], zero-pad k in [K, KS).
// ---------------------------------------------------------------------------
__global__ void prep_k(const float* __restrict__ src, f16* __restrict__ dst,
                       int K, int N, int KS, long srcMat, long dstMat)
{
    __shared__ float tile[32][33];
    const int m = blockIdx.y;
    const int ktiles = KS >> 5;
    const int kt = blockIdx.x % ktiles, nt = blockIdx.x / ktiles;
    const int tx = threadIdx.x, ty = threadIdx.y;
    const float* s = src + (long)m * srcMat;
    f16* d = dst + (long)m * dstMat;
    #pragma unroll
    for (int j = 0; j < 4; j++) {
        int k = kt * 32 + ty + j * 8, n = nt * 32 + tx;
        tile[ty + j * 8][tx] = (k < K && n < N) ? s[(long)k * N + n] : 0.f;
    }
    __syncthreads();
    #pragma unroll
    for (int j = 0; j < 4; j++) {
        int n = nt * 32 + ty + j * 8, k = kt * 32 + tx;
        if (n < N) d[(long)n * KS + k] = (f16)tile[tx][ty + j * 8];
    }
}

// ---------------------------------------------------------------------------
// inv_k: invp[i][perm[i][d]] = d
// ---------------------------------------------------------------------------
__global__ void inv_k(const int* __restrict__ perms, int* __restrict__ invp)
{
    const int i = blockIdx.x;
    for (int d = threadIdx.x; d < DF; d += 256) {
        int src = perms[(long)i * DF + d];
        invp[(long)i * DF + src] = d;
    }
}

// ---------------------------------------------------------------------------
// GEMM1: Hb[b][n] = relu( sum_k Wf[n][k]*A[b][k] + Wcond[l[b]][n] + bias[n] )
// Tile 64n x 64b, double-buffered LDS, grid (8, 64), block 256 (4 waves 2x2).
// ---------------------------------------------------------------------------
__global__ __launch_bounds__(256)
void gemm1_k(const f16* __restrict__ A, long apitch,
             const f16* __restrict__ Wf, const float* __restrict__ Wcond,
             const float* __restrict__ bias, const int* __restrict__ lvec,
             f16* __restrict__ Hb)
{
    __shared__ __align__(16) f16 Al[2][64 * 64];

    const int tid  = threadIdx.x;
    const int n0   = blockIdx.x * 64;
    const int b0   = blockIdx.y * 64;
    const int wid  = tid >> 6, lane = tid & 63;
    const int wn   = wid >> 1, wb = wid & 1;
    const int ln16 = lane & 15, koct = lane >> 4;

    const int br  = tid & 63;          // staged LDS row (b)
    const int c0  = tid >> 6;          // stages chunks c0 and c0+4
    const int sw0 = (c0 ^ (br & 7)) * 8;
    const int sw1 = ((c0 + 4) ^ (br & 7)) * 8;

    const f16* Arow = &A[(long)(b0 + br) * apitch];
    const f16* Wrow = &Wf[(long)(n0 + wn * 32 + ln16) * KS1 + koct * 8];

    fx4 acc[2][2];
    #pragma unroll
    for (int i = 0; i < 2; i++)
        #pragma unroll
        for (int j = 0; j < 2; j++) acc[i][j] = (fx4)0.f;

    // prologue: stage tile 0 + W frags for tile 0
    half8v sa = *(const half8v*)&Arow[c0 * 8];
    half8v sb = *(const half8v*)&Arow[(c0 + 4) * 8];
    half8v afc[2][2], afn[2][2];
    #pragma unroll
    for (int ks = 0; ks < 2; ks++)
        #pragma unroll
        for (int ni = 0; ni < 2; ni++)
            afc[ks][ni] = *(const half8v*)&Wrow[(long)ni * 16 * KS1 + ks * 32];
    *(half8v*)&Al[0][br * 64 + sw0] = sa;
    *(half8v*)&Al[0][br * 64 + sw1] = sb;
    __syncthreads();

    #pragma unroll
    for (int t = 0; t < NT1; t++) {
        const int cur = t & 1;
        if (t + 1 < NT1) {
            const int k0 = (t + 1) * 64;
            sa = *(const half8v*)&Arow[k0 + c0 * 8];
            sb = *(const half8v*)&Arow[k0 + (c0 + 4) * 8];
            #pragma unroll
            for (int ks = 0; ks < 2; ks++)
                #pragma unroll
                for (int ni = 0; ni < 2; ni++)
                    afn[ks][ni] = *(const half8v*)&Wrow[(long)ni * 16 * KS1 + k0 + ks * 32];
        }
        #pragma unroll
        for (int ks = 0; ks < 2; ks++) {
            half8v bf[2];
            #pragma unroll
            for (int bi = 0; bi < 2; bi++) {
                int b = wb * 32 + bi * 16 + ln16;
                int c = (ks * 4 + koct) ^ (b & 7);
                bf[bi] = *(const half8v*)&Al[cur][b * 64 + c * 8];
            }
            #pragma unroll
            for (int ni = 0; ni < 2; ni++)
                #pragma unroll
                for (int bi = 0; bi < 2; bi++)
                    acc[ni][bi] = __builtin_amdgcn_mfma_f32_16x16x32_f16(afc[ks][ni], bf[bi], acc[ni][bi], 0, 0, 0);
        }
        if (t + 1 < NT1) {
            *(half8v*)&Al[cur ^ 1][br * 64 + sw0] = sa;
            *(half8v*)&Al[cur ^ 1][br * 64 + sw1] = sb;
            #pragma unroll
            for (int ks = 0; ks < 2; ks++)
                #pragma unroll
                for (int ni = 0; ni < 2; ni++)
                    afc[ks][ni] = afn[ks][ni];
        }
        __syncthreads();
    }

    // epilogue: + bias + cond row, relu, store Hb[b][n]
    #pragma unroll
    for (int bi = 0; bi < 2; bi++) {
        int b = b0 + wb * 32 + bi * 16 + ln16;
        int lvb = lvec[b];
        const float* crow = Wcond + (long)lvb * HIDF;
        #pragma unroll
        for (int ni = 0; ni < 2; ni++) {
            int nb = n0 + wn * 32 + ni * 16 + koct * 4;
            half4v o;
            #pragma unroll
            for (int r = 0; r < 4; r++) {
                float v = acc[ni][bi][r] + bias[nb + r] + crow[nb + r];
                o[r] = (f16)fmaxf(v, 0.f);
            }
            *(half4v*)&Hb[(long)b * HIDF + nb] = o;
        }
    }
}

// ---------------------------------------------------------------------------
// Fused GEMM2 + coupling + scatter into next P.
//   s = sum_k Wf[d][k]*Hb[b][k] + bias[d];  t = (d+392 row)
//   ls = 0.636*atan(s); y = exp(ls)*Px[b][d] + t
//   Y[b][d] = y;  if (Pn) Pn[b][invp[d]] = y;  jac[b] += sum ls
// Tile 32d x 64b, grid (13, 64), block 256.
// ---------------------------------------------------------------------------
__global__ __launch_bounds__(256)
void gemm2c_k(const f16* __restrict__ Hb, const f16* __restrict__ Wf,
              const float* __restrict__ bias, const f16* __restrict__ Px,
              f16* __restrict__ Y, float* __restrict__ jac,
              f16* __restrict__ Pn, const int* __restrict__ invp)
{
    __shared__ __align__(16) f16 Bl[2][64 * 64];

    const int tid  = threadIdx.x;
    const int d0   = blockIdx.x * 32;
    const int b0   = blockIdx.y * 64;
    const int wid  = tid >> 6, lane = tid & 63;
    const int wn   = wid >> 1, wb = wid & 1;
    const int ln16 = lane & 15, koct = lane >> 4;

    const int br  = tid & 63;
    const int c0  = tid >> 6;
    const int sw0 = (c0 ^ (br & 7)) * 8;
    const int sw1 = ((c0 + 4) ^ (br & 7)) * 8;

    const int dr  = d0 + wn * 16 + ln16;
    const int drc = (dr < HALFF) ? dr : (HALFF - 1);
    const f16* Hrow = &Hb[(long)(b0 + br) * HIDF];
    const f16* Wrow = &Wf[(long)drc * KS2 + koct * 8];

    fx4 acc[2][2];   // [s/t][bi]
    #pragma unroll
    for (int i = 0; i < 2; i++)
        #pragma unroll
        for (int j = 0; j < 2; j++) acc[i][j] = (fx4)0.f;

    half8v sa = *(const half8v*)&Hrow[c0 * 8];
    half8v sb = *(const half8v*)&Hrow[(c0 + 4) * 8];
    half8v afc[2][2], afn[2][2];
    #pragma unroll
    for (int ks = 0; ks < 2; ks++) {
        afc[ks][0] = *(const half8v*)&Wrow[ks * 32];
        afc[ks][1] = *(const half8v*)&Wrow[(long)HALFF * KS2 + ks * 32];
    }
    *(half8v*)&Bl[0][br * 64 + sw0] = sa;
    *(half8v*)&Bl[0][br * 64 + sw1] = sb;
    __syncthreads();

    #pragma unroll
    for (int t = 0; t < NT2; t++) {
        const int cur = t & 1;
        if (t + 1 < NT2) {
            const int k0 = (t + 1) * 64;
            sa = *(const half8v*)&Hrow[k0 + c0 * 8];
            sb = *(const half8v*)&Hrow[k0 + (c0 + 4) * 8];
            #pragma unroll
            for (int ks = 0; ks < 2; ks++) {
                afn[ks][0] = *(const half8v*)&Wrow[k0 + ks * 32];
                afn[ks][1] = *(const half8v*)&Wrow[(long)HALFF * KS2 + k0 + ks * 32];
            }
        }
        #pragma unroll
        for (int ks = 0; ks < 2; ks++) {
            half8v bf[2];
            #pragma unroll
            for (int bi = 0; bi < 2; bi++) {
                int b = wb * 32 + bi * 16 + ln16;
                int c = (ks * 4 + koct) ^ (b & 7);
                bf[bi] = *(const half8v*)&Bl[cur][b * 64 + c * 8];
            }
            #pragma unroll
            for (int ni = 0; ni < 2; ni++)
                #pragma unroll
                for (int bi = 0; bi < 2; bi++)
                    acc[ni][bi] = __builtin_amdgcn_mfma_f32_16x16x32_f16(afc[ks][ni], bf[bi], acc[ni][bi], 0, 0, 0);
        }
        if (t + 1 < NT2) {
            *(half8v*)&Bl[cur ^ 1][br * 64 + sw0] = sa;
            *(half8v*)&Bl[cur ^ 1][br * 64 + sw1] = sb;
            #pragma unroll
            for (int ks = 0; ks < 2; ks++)
                #pragma unroll
                for (int ni = 0; ni < 2; ni++)
                    afc[ks][ni] = afn[ks][ni];
        }
        __syncthreads();
    }

    // ---- fused coupling epilogue (dbase quad fully valid or fully not)
    const int dbase = d0 + wn * 16 + koct * 4;
    const bool dok = (dbase < HALFF);
    #pragma unroll
    for (int bi = 0; bi < 2; bi++) {
        int b = b0 + wb * 32 + bi * 16 + ln16;
        float jp = 0.f;
        if (dok) {
            half4v xv = *(const half4v*)&Px[(long)b * PP + dbase];
            half4v o;
            #pragma unroll
            for (int r = 0; r < 4; r++) {
                float s  = acc[0][bi][r] + bias[dbase + r];
                float tt = acc[1][bi][r] + bias[dbase + r + HALFF];
                float ls = 0.636f * atanf(s);
                jp += ls;
                o[r] = (f16)(expf(ls) * (float)xv[r] + tt);
            }
            *(half4v*)&Y[(long)b * YP + dbase] = o;
            if (Pn) {
                ix4 iv = *(const ix4*)&invp[dbase];
                #pragma unroll
                for (int r = 0; r < 4; r++)
                    Pn[(long)b * PP + iv[r]] = o[r];
            }
        }
        jp += __shfl_xor(jp, 16);
        jp += __shfl_xor(jp, 32);
        if (koct == 0)
            atomicAdd(&jac[b], jp);
    }
}

// ---------------------------------------------------------------------------
// tin_pm: P0[b][dpos] = (f16) x[b][perm0[dpos]].  grid (98,16), block 256.
// ---------------------------------------------------------------------------
__global__ __launch_bounds__(256)
void tin_pm_k(const float* __restrict__ x, const int* __restrict__ perm,
              f16* __restrict__ P)
{
    const int dp = blockIdx.x * 8;
    const int b  = blockIdx.y * 256 + threadIdx.x;
    half8v o;
    #pragma unroll
    for (int j = 0; j < 8; j++) {
        int r = perm[dp + j];
        o[j] = (f16)x[(long)b * DF + r];
    }
    *(half8v*)&P[(long)b * PP + dp] = o;
}

// fin_k: out[b][d] = fp32(concat(Y1,Y2)[b][d]).
__global__ __launch_bounds__(256)
void fin_k(const f16* __restrict__ Y1, const f16* __restrict__ Y2,
           float* __restrict__ out)
{
    const int b = blockIdx.x;
    const int d = threadIdx.x * 4;
    if (d < DF) {
        const f16* src = (d < HALFF) ? &Y1[(long)b * YP + d]
                                     : &Y2[(long)b * YP + d - HALFF];
        half4v v = *(const half4v*)src;
        fx4 o;
        #pragma unroll
        for (int r = 0; r < 4; r++) o[r] = (float)v[r];
        *(fx4*)&out[(long)b * DF + d] = o;
    }
}

__global__ void zero_k(float* __restrict__ p)
{
    p[blockIdx.x * 256 + threadIdx.x] = 0.f;
}

__global__ void cjac_k(const float* __restrict__ jac, float* __restrict__ out)
{
    int i = blockIdx.x * 256 + threadIdx.x;
    out[i] = jac[i];
}

// ---------------------------------------------------------------------------
extern "C" void kernel_launch(void* const* d_in, const int* in_sizes, int n_in,
                              void* d_out, int out_size, void* d_ws, size_t ws_size,
                              hipStream_t stream)
{
    const float* x     = (const float*)d_in[0];
    const int*   l     = (const int*)d_in[1];
    const int*   perms = (const int*)d_in[2];
    const float* s1W1  = (const float*)d_in[3];
    const float* s1b1  = (const float*)d_in[4];
    const float* s1W2  = (const float*)d_in[5];
    const float* s1b2  = (const float*)d_in[6];
    const float* s2W1  = (const float*)d_in[7];
    const float* s2b1  = (const float*)d_in[8];
    const float* s2W2  = (const float*)d_in[9];
    const float* s2b2  = (const float*)d_in[10];
    float* out = (float*)d_out;

    char* ws = (char*)d_ws;
    const size_t PB = (size_t)BN * PP * 2;            // 6.95 MB
    const size_t YB = (size_t)BN * YP * 2;            // 3.67 MB
    f16*   Pa   = (f16*)ws;
    f16*   Pb   = (f16*)(ws + PB);
    f16*   Y1   = (f16*)(ws + 2 * PB);
    f16*   Y2   = (f16*)(ws + 2 * PB + YB);
    f16*   Hb   = (f16*)(ws + 2 * PB + 2 * YB);       // 4.19 MB
    float* jac  = (float*)(ws + 2 * PB + 2 * YB + (size_t)BN * HIDF * 2);
    int*   invp = (int*)((char*)jac + 65536);
    f16*   wb   = (f16*)((char*)invp + 65536);

    const long W1E = (long)HIDF * KS1;
    const long W2E = (long)DF * KS2;
    f16* Wf1_s2 = wb;
    f16* Wf1_s1 = Wf1_s2 + W1E * NBLK;
    f16* Wf2_s2 = Wf1_s1 + W1E * NBLK;
    f16* Wf2_s1 = Wf2_s2 + W2E * NBLK;

    dim3 pb(32, 8);
    prep_k<<<dim3((KS1 / 32) * 16, NBLK), pb, 0, stream>>>(s2W1, Wf1_s2, HALFF, HIDF, KS1, 402L * 512, W1E);
    prep_k<<<dim3((KS1 / 32) * 16, NBLK), pb, 0, stream>>>(s1W1, Wf1_s1, HALFF, HIDF, KS1, 402L * 512, W1E);
    prep_k<<<dim3((KS2 / 32) * 25, NBLK), pb, 0, stream>>>(s2W2, Wf2_s2, HIDF, DF, KS2, 512L * 784, W2E);
    prep_k<<<dim3((KS2 / 32) * 25, NBLK), pb, 0, stream>>>(s1W2, Wf2_s1, HIDF, DF, KS2, 512L * 784, W2E);

    inv_k<<<NBLK, 256, 0, stream>>>(perms, invp);
    tin_pm_k<<<dim3(98, 16), 256, 0, stream>>>(x, perms, Pa);
    zero_k<<<16, 256, 0, stream>>>(jac);

    f16* Pc = Pa;
    f16* Po = Pb;
    for (int i = 0; i < NBLK; i++) {
        f16* Pnx = (i < NBLK - 1) ? Po : nullptr;
        const int* ivn = invp + (long)((i + 1) % NBLK) * DF;
        // substep 2: A = x2 = Pc[:,392:], x-mult = x1 = Pc[:,0:392] -> Y1
        gemm1_k<<<dim3(8, 64), 256, 0, stream>>>(Pc + HALFF, (long)PP,
                Wf1_s2 + i * W1E, s2W1 + (long)i * 402 * 512 + (long)HALFF * HIDF,
                s2b1 + (long)i * 512, l, Hb);
        gemm2c_k<<<dim3(13, 64), 256, 0, stream>>>(Hb, Wf2_s2 + i * W2E,
                s2b2 + (long)i * 784, Pc, Y1, jac, Pnx, ivn);
        // substep 1: A = y1 = Y1, x-mult = x2 = Pc[:,392:] -> Y2
        gemm1_k<<<dim3(8, 64), 256, 0, stream>>>(Y1, (long)YP,
                Wf1_s1 + i * W1E, s1W1 + (long)i * 402 * 512 + (long)HALFF * HIDF,
                s1b1 + (long)i * 512, l, Hb);
        gemm2c_k<<<dim3(13, 64), 256, 0, stream>>>(Hb, Wf2_s1 + i * W2E,
                s1b2 + (long)i * 784, Pc + HALFF, Y2, jac, Pnx, ivn + HALFF);
        f16* tmp = Pc; Pc = Po; Po = tmp;
    }

    fin_k<<<4096, 256, 0, stream>>>(Y1, Y2, out);
    cjac_k<<<16, 256, 0, stream>>>(jac, out + (long)BN * DF);
}

// Round 6
// 1848.062 us; speedup vs baseline: 1.1325x; 1.1325x over previous
//
#include <hip/hip_runtime.h>

#define BN 4096
#define DF 784
#define HALFF 392
#define HIDF 512
#define NBLK 20
#define KS1 448      // padded K for GEMM1 (392 -> 7*64)
#define KS2 512      // K for GEMM2
#define BT 16        // batch rows per block
#define NW 8         // waves per block
#define THREADS 512

// LDS half-offsets
#define X1o 0
#define X2o 7168
#define Y1o 14336
#define Y2o 21504
#define Ho  28672
#define SMH 36864    // total halves (73728 B)

typedef _Float16 f16;
typedef _Float16 half4v __attribute__((ext_vector_type(4)));
typedef _Float16 half8v __attribute__((ext_vector_type(8)));
typedef float    fx4    __attribute__((ext_vector_type(4)));
typedef int      ix4    __attribute__((ext_vector_type(4)));

// swizzled LDS index (halves): 8-half chunks XOR'd by row&7 within 64-half groups
__device__ __forceinline__ int lad(int base, int b, int k, int pitch)
{
    return base + b * pitch + (k & ~63) + ((((k >> 3) & 7) ^ (b & 7)) << 3) + (k & 7);
}

// ---------------------------------------------------------------------------
// prep_k: fp32 weights [m][k][N] -> fp16 [m][n][KS], zero-pad k in [K, KS).
// ---------------------------------------------------------------------------
__global__ void prep_k(const float* __restrict__ src, f16* __restrict__ dst,
                       int K, int N, int KS, long srcMat, long dstMat)
{
    __shared__ float tile[32][33];
    const int m = blockIdx.y;
    const int ktiles = KS >> 5;
    const int kt = blockIdx.x % ktiles, nt = blockIdx.x / ktiles;
    const int tx = threadIdx.x, ty = threadIdx.y;
    const float* s = src + (long)m * srcMat;
    f16* d = dst + (long)m * dstMat;
    #pragma unroll
    for (int j = 0; j < 4; j++) {
        int k = kt * 32 + ty + j * 8, n = nt * 32 + tx;
        tile[ty + j * 8][tx] = (k < K && n < N) ? s[(long)k * N + n] : 0.f;
    }
    __syncthreads();
    #pragma unroll
    for (int j = 0; j < 4; j++) {
        int n = nt * 32 + ty + j * 8, k = kt * 32 + tx;
        if (n < N) d[(long)n * KS + k] = (f16)tile[tx][ty + j * 8];
    }
}

// c16[m][cls][n] = W1[m][392+cls][n] + b1[m][n]  (bias folded), fp16
__global__ void prep_c16_k(const float* __restrict__ W1, const float* __restrict__ b1,
                           f16* __restrict__ dst)
{
    const int m = blockIdx.x;
    for (int idx = threadIdx.x; idx < 10 * HIDF; idx += 256) {
        int cls = idx >> 9, n = idx & 511;
        dst[(long)m * 10 * HIDF + idx] =
            (f16)(W1[(long)m * 402 * 512 + (long)(HALFF + cls) * 512 + n] + b1[(long)m * HIDF + n]);
    }
}

__global__ void inv_k(const int* __restrict__ perms, int* __restrict__ invp)
{
    const int i = blockIdx.x;
    for (int d = threadIdx.x; d < DF; d += 256) {
        int src = perms[(long)i * DF + d];
        invp[(long)i * DF + src] = d;
    }
}

// ---------------------------------------------------------------------------
// GEMM1 phase: H[b][n] = relu( sum_k Wf[n][k]*A[b][k] + C16[cls[b]][n] )
// per wave: 4 n-tiles (n = wid*64 + j*16), K = 14 slices of 32.
// ---------------------------------------------------------------------------
__device__ __forceinline__ void do_gemm1(f16* SM, const f16* __restrict__ Wf,
                                         const f16* __restrict__ C16,
                                         int Ao, int clsr, int wid, int ln16, int koct)
{
    fx4 acc[4] = {};
    const f16* wr[4];
    #pragma unroll
    for (int j = 0; j < 4; j++)
        wr[j] = Wf + (long)(wid * 64 + j * 16 + ln16) * KS1 + koct * 8;
    #pragma unroll
    for (int sl = 0; sl < 14; sl++) {
        half8v a = *(const half8v*)&SM[lad(Ao, ln16, sl * 32 + koct * 8, KS1)];
        #pragma unroll
        for (int j = 0; j < 4; j++) {
            half8v w = *(const half8v*)&wr[j][sl * 32];
            acc[j] = __builtin_amdgcn_mfma_f32_16x16x32_f16(w, a, acc[j], 0, 0, 0);
        }
    }
    #pragma unroll
    for (int j = 0; j < 4; j++) {
        int nb = wid * 64 + j * 16 + koct * 4;
        half4v c = *(const half4v*)&C16[clsr * HIDF + nb];
        half4v o;
        #pragma unroll
        for (int r = 0; r < 4; r++)
            o[r] = (f16)fmaxf(acc[j][r] + (float)c[r], 0.f);
        *(half4v*)&SM[lad(Ho, ln16, nb, HIDF)] = o;
    }
}

// coupling epilogue for one (s,t) quad
__device__ __forceinline__ float couple_store(f16* SM, const float* __restrict__ b2,
                                              int Xmo, int Yo, int dbase, int ln16,
                                              fx4 sac, fx4 tac)
{
    float jp = 0.f;
    if (dbase + 3 < HALFF) {
        fx4 bs = *(const fx4*)&b2[dbase];
        fx4 bt = *(const fx4*)&b2[dbase + HALFF];
        half4v xv = *(const half4v*)&SM[lad(Xmo, ln16, dbase, KS1)];
        half4v o;
        #pragma unroll
        for (int r = 0; r < 4; r++) {
            float s  = sac[r] + bs[r];
            float tt = tac[r] + bt[r];
            float ls = 0.636f * atanf(s);
            jp += ls;
            o[r] = (f16)(expf(ls) * (float)xv[r] + tt);
        }
        *(half4v*)&SM[lad(Yo, ln16, dbase, KS1)] = o;
    }
    return jp;
}

// ---------------------------------------------------------------------------
// GEMM2+coupling phase: s/t rows paired (d, d+392); 25 d-tiles of 16:
// waves get pairs {wid, wid+8, wid+16}; wave 0 also does pair 24 (rows clamped).
// ---------------------------------------------------------------------------
__device__ __forceinline__ float do_gemm2(f16* SM, const f16* __restrict__ Wf,
                                          const float* __restrict__ b2,
                                          int Xmo, int Yo, int wid, int ln16, int koct)
{
    float jp = 0.f;
    {
        fx4 sac[3] = {}, tac[3] = {};
        const f16 *ws[3], *wt[3];
        #pragma unroll
        for (int j = 0; j < 3; j++) {
            int d = (wid + j * 8) * 16 + ln16;          // <= 383, no clamp
            ws[j] = Wf + (long)d * KS2 + koct * 8;
            wt[j] = Wf + (long)(d + HALFF) * KS2 + koct * 8;
        }
        #pragma unroll
        for (int sl = 0; sl < 16; sl++) {
            half8v a = *(const half8v*)&SM[lad(Ho, ln16, sl * 32 + koct * 8, HIDF)];
            #pragma unroll
            for (int j = 0; j < 3; j++) {
                half8v w0 = *(const half8v*)&ws[j][sl * 32];
                half8v w1 = *(const half8v*)&wt[j][sl * 32];
                sac[j] = __builtin_amdgcn_mfma_f32_16x16x32_f16(w0, a, sac[j], 0, 0, 0);
                tac[j] = __builtin_amdgcn_mfma_f32_16x16x32_f16(w1, a, tac[j], 0, 0, 0);
            }
        }
        #pragma unroll
        for (int j = 0; j < 3; j++)
            jp += couple_store(SM, b2, Xmo, Yo, (wid + j * 8) * 16 + koct * 4, ln16, sac[j], tac[j]);
    }
    if (wid == 0) {   // tail pair 24: d rows 384..399, clamp rows >= 392 (results discarded)
        fx4 sac = {}, tac = {};
        int dr = 384 + ln16;
        int drc = (dr < HALFF) ? dr : (HALFF - 1);
        const f16* ws = Wf + (long)drc * KS2 + koct * 8;
        const f16* wt = Wf + (long)(drc + HALFF) * KS2 + koct * 8;
        #pragma unroll
        for (int sl = 0; sl < 16; sl++) {
            half8v a = *(const half8v*)&SM[lad(Ho, ln16, sl * 32 + koct * 8, HIDF)];
            half8v w0 = *(const half8v*)&ws[sl * 32];
            half8v w1 = *(const half8v*)&wt[sl * 32];
            sac = __builtin_amdgcn_mfma_f32_16x16x32_f16(w0, a, sac, 0, 0, 0);
            tac = __builtin_amdgcn_mfma_f32_16x16x32_f16(w1, a, tac, 0, 0, 0);
        }
        jp += couple_store(SM, b2, Xmo, Yo, 384 + koct * 4, ln16, sac, tac);
    }
    return jp;
}

// ---------------------------------------------------------------------------
// mega kernel: one block = 16 batch rows, entire 20-block cINN in LDS.
// grid 256, block 512 (8 waves).
// ---------------------------------------------------------------------------
__global__ __launch_bounds__(THREADS, 2)
void mega_k(const float* __restrict__ x, const int* __restrict__ lvec,
            const int* __restrict__ perms, const int* __restrict__ invp,
            const f16* __restrict__ Wf1a, const f16* __restrict__ Wf1b,
            const f16* __restrict__ Wf2a, const f16* __restrict__ Wf2b,
            const f16* __restrict__ C16a, const f16* __restrict__ C16b,
            const float* __restrict__ b2a, const float* __restrict__ b2b,
            float* __restrict__ outp)
{
    __shared__ __align__(16) f16 SM[SMH];
    __shared__ float JR[NW][BT];
    const int tid  = threadIdx.x;
    const int wid  = tid >> 6, lane = tid & 63;
    const int ln16 = lane & 15, koct = lane >> 4;
    const int b0g  = blockIdx.x * BT;
    const int clsr = lvec[b0g + ln16];

    // zero pads of X2 and Y1 (cols [392,448))
    half8v hz = {};
    for (int idx = tid; idx < 2 * BT * 7; idx += THREADS) {
        int buf = idx / (BT * 7);
        int rem = idx - buf * (BT * 7);
        int b = rem / 7, g = rem - (rem / 7) * 7;
        *(half8v*)&SM[lad(buf ? Y1o : X2o, b, HALFF + g * 8, KS1)] = hz;
    }
    // initial load: X = x[b][perm0-gather] via inverse perm scatter (coalesced reads)
    for (int idx = tid; idx < BT * (DF / 4); idx += THREADS) {
        int b = idx / (DF / 4);
        int q = (idx - b * (DF / 4)) * 4;
        fx4 v = *(const fx4*)&x[(long)(b0g + b) * DF + q];
        ix4 iv = *(const ix4*)&invp[q];
        #pragma unroll
        for (int r = 0; r < 4; r++) {
            int dp = iv[r];
            if (dp < HALFF) SM[lad(X1o, b, dp, KS1)] = (f16)v[r];
            else            SM[lad(X2o, b, dp - HALFF, KS1)] = (f16)v[r];
        }
    }
    __syncthreads();

    float jacc = 0.f;
    #pragma unroll 1
    for (int i = 0; i < NBLK; i++) {
        // substep 2: H = relu(X2@W1 + cond); (s,t) = H@W2; Y1 = exp(ls)*X1 + t
        do_gemm1(SM, Wf1a + (long)i * HIDF * KS1, C16a + (long)i * 10 * HIDF,
                 X2o, clsr, wid, ln16, koct);
        __syncthreads();
        jacc += do_gemm2(SM, Wf2a + (long)i * DF * KS2, b2a + (long)i * DF,
                         X1o, Y1o, wid, ln16, koct);
        __syncthreads();
        // substep 1: H = relu(Y1@W1 + cond); Y2 = exp(ls)*X2 + t
        do_gemm1(SM, Wf1b + (long)i * HIDF * KS1, C16b + (long)i * 10 * HIDF,
                 Y1o, clsr, wid, ln16, koct);
        __syncthreads();
        jacc += do_gemm2(SM, Wf2b + (long)i * DF * KS2, b2b + (long)i * DF,
                         X2o, Y2o, wid, ln16, koct);
        __syncthreads();
        if (i < NBLK - 1) {
            const int* pm = perms + (long)(i + 1) * DF;
            for (int dp = tid; dp < DF; dp += THREADS) {
                int src = pm[dp];
                int so  = (src < HALFF) ? Y1o : Y2o;
                int sk  = (src < HALFF) ? src : src - HALFF;
                int dbo = (dp < HALFF) ? X1o : X2o;
                int dk  = (dp < HALFF) ? dp : dp - HALFF;
                #pragma unroll
                for (int b = 0; b < BT; b++)
                    SM[lad(dbo, b, dk, KS1)] = SM[lad(so, b, sk, KS1)];
            }
            __syncthreads();
        }
    }

    // output z = concat(Y1, Y2) in fp32
    for (int idx = tid; idx < BT * (DF / 4); idx += THREADS) {
        int b = idx / (DF / 4);
        int q = (idx - b * (DF / 4)) * 4;
        int so = (q < HALFF) ? Y1o : Y2o;
        int kk = (q < HALFF) ? q : q - HALFF;
        half4v v = *(const half4v*)&SM[lad(so, b, kk, KS1)];
        fx4 o;
        #pragma unroll
        for (int r = 0; r < 4; r++) o[r] = (float)v[r];
        *(fx4*)&outp[(long)(b0g + b) * DF + q] = o;
    }
    // jac reduce: koct groups -> waves -> block
    float j1 = jacc + __shfl_xor(jacc, 16);
    j1 += __shfl_xor(j1, 32);
    if (koct == 0) JR[wid][ln16] = j1;
    __syncthreads();
    if (tid < BT) {
        float s = 0.f;
        #pragma unroll
        for (int w = 0; w < NW; w++) s += JR[w][tid];
        outp[(long)BN * DF + b0g + tid] = s;
    }
}

// ---------------------------------------------------------------------------
extern "C" void kernel_launch(void* const* d_in, const int* in_sizes, int n_in,
                              void* d_out, int out_size, void* d_ws, size_t ws_size,
                              hipStream_t stream)
{
    const float* x     = (const float*)d_in[0];
    const int*   l     = (const int*)d_in[1];
    const int*   perms = (const int*)d_in[2];
    const float* s1W1  = (const float*)d_in[3];
    const float* s1b1  = (const float*)d_in[4];
    const float* s1W2  = (const float*)d_in[5];
    const float* s1b2  = (const float*)d_in[6];
    const float* s2W1  = (const float*)d_in[7];
    const float* s2b1  = (const float*)d_in[8];
    const float* s2W2  = (const float*)d_in[9];
    const float* s2b2  = (const float*)d_in[10];
    float* out = (float*)d_out;

    const long W1E = (long)HIDF * KS1;
    const long W2E = (long)DF * KS2;
    f16* Wf1a = (f16*)d_ws;                       // s2 W1
    f16* Wf1b = Wf1a + W1E * NBLK;                // s1 W1
    f16* Wf2a = Wf1b + W1E * NBLK;                // s2 W2
    f16* Wf2b = Wf2a + W2E * NBLK;                // s1 W2
    f16* C16a = Wf2b + W2E * NBLK;
    f16* C16b = C16a + (long)NBLK * 10 * HIDF;
    int* invp = (int*)(C16b + (long)NBLK * 10 * HIDF);

    dim3 pb(32, 8);
    prep_k<<<dim3((KS1 / 32) * 16, NBLK), pb, 0, stream>>>(s2W1, Wf1a, HALFF, HIDF, KS1, 402L * 512, W1E);
    prep_k<<<dim3((KS1 / 32) * 16, NBLK), pb, 0, stream>>>(s1W1, Wf1b, HALFF, HIDF, KS1, 402L * 512, W1E);
    prep_k<<<dim3((KS2 / 32) * 25, NBLK), pb, 0, stream>>>(s2W2, Wf2a, HIDF, DF, KS2, 512L * 784, W2E);
    prep_k<<<dim3((KS2 / 32) * 25, NBLK), pb, 0, stream>>>(s1W2, Wf2b, HIDF, DF, KS2, 512L * 784, W2E);
    prep_c16_k<<<NBLK, 256, 0, stream>>>(s2W1, s2b1, C16a);
    prep_c16_k<<<NBLK, 256, 0, stream>>>(s1W1, s1b1, C16b);
    inv_k<<<NBLK, 256, 0, stream>>>(perms, invp);

    mega_k<<<BN / BT, THREADS, 0, stream>>>(x, l, perms, invp,
            Wf1a, Wf1b, Wf2a, Wf2b, C16a, C16b, s2b2, s1b2, out);
}

// Round 7
// 841.032 us; speedup vs baseline: 2.4885x; 2.1974x over previous
//
#include <hip/hip_runtime.h>

#define BN 4096
#define DF 784
#define HALFF 392
#define HIDF 512
#define NBLK 20
#define KS1 448      // padded K for GEMM1 (392 -> 14*32)
#define KS2 512      // K for GEMM2 (16*32)
#define BT 16        // batch rows per block
#define NW 8         // waves per block
#define THREADS 512

// LDS half-offsets (X/Y pitch KS1, H pitch HIDF)
#define Y1o 28672
#define Y2o 35840
#define Ho  43008
#define SMH 51200    // 102400 B

typedef _Float16 f16;
typedef _Float16 half4v __attribute__((ext_vector_type(4)));
typedef _Float16 half8v __attribute__((ext_vector_type(8)));
typedef float    fx4    __attribute__((ext_vector_type(4)));
typedef int      ix4    __attribute__((ext_vector_type(4)));

// swizzled LDS index (halves): 8-half chunks XOR'd by row&7 within 64-half groups
__device__ __forceinline__ int lad(int base, int b, int k, int pitch)
{
    return base + b * pitch + (k & ~63) + ((((k >> 3) & 7) ^ (b & 7)) << 3) + (k & 7);
}

// ---------------------------------------------------------------------------
// pack1_k: W1 fp32 [m][402][512] -> fragment-major fp16
//   Wpk1[m][ntile=32][sl=14][lane=64][8],  lane l -> row n = ntile*16+(l&15),
//   k = sl*32+(l>>4)*8+e, zero for k >= 392.  grid (448, 20), block 64.
// ---------------------------------------------------------------------------
__global__ void pack1_k(const float* __restrict__ W1, f16* __restrict__ dst)
{
    const int m = blockIdx.y;
    const int nt = blockIdx.x / 14, sl = blockIdx.x % 14;
    const int l = threadIdx.x;
    const int n = nt * 16 + (l & 15);
    const int kb = sl * 32 + (l >> 4) * 8;
    const float* src = W1 + (long)m * 402 * 512;
    half8v o;
    #pragma unroll
    for (int e = 0; e < 8; e++) {
        int k = kb + e;
        o[e] = (k < HALFF) ? (f16)src[(long)k * 512 + n] : (f16)0.f;
    }
    *(half8v*)&dst[(((long)(m * 32 + nt) * 14) + sl) * 512 + l * 8] = o;
}

// ---------------------------------------------------------------------------
// pack2_k: W2 fp32 [m][512][784] -> Wpk2[m][dt=25][sl=16][c=2][lane][8]
//   c=0: s-row d=min(dt*16+(l&15),391); c=1: t-row d+392.
//   grid (400, 20), block 128.
// ---------------------------------------------------------------------------
__global__ void pack2_k(const float* __restrict__ W2, f16* __restrict__ dst)
{
    const int m = blockIdx.y;
    const int dt = blockIdx.x / 16, sl = blockIdx.x % 16;
    const int c = threadIdx.x >> 6, l = threadIdx.x & 63;
    int dr = dt * 16 + (l & 15);
    if (dr >= HALFF) dr = HALFF - 1;
    const int d = dr + c * HALFF;
    const int kb = sl * 32 + (l >> 4) * 8;
    const float* src = W2 + (long)m * 512 * 784;
    half8v o;
    #pragma unroll
    for (int e = 0; e < 8; e++)
        o[e] = (f16)src[(long)(kb + e) * 784 + d];
    *(half8v*)&dst[((((long)(m * 25 + dt) * 16) + sl) * 2 + c) * 512 + l * 8] = o;
}

// c16[m][cls][n] = W1[m][392+cls][n] + b1[m][n]  (bias folded), fp16
__global__ void prep_c16_k(const float* __restrict__ W1, const float* __restrict__ b1,
                           f16* __restrict__ dst)
{
    const int m = blockIdx.x;
    for (int idx = threadIdx.x; idx < 10 * HIDF; idx += 256) {
        int cls = idx >> 9, n = idx & 511;
        dst[(long)m * 10 * HIDF + idx] =
            (f16)(W1[(long)m * 402 * 512 + (long)(HALFF + cls) * 512 + n] + b1[(long)m * HIDF + n]);
    }
}

__global__ void inv_k(const int* __restrict__ perms, int* __restrict__ invp)
{
    const int i = blockIdx.x;
    for (int d = threadIdx.x; d < DF; d += 256) {
        int src = perms[(long)i * DF + d];
        invp[(long)i * DF + src] = d;
    }
}

// ---------------------------------------------------------------------------
// GEMM1 phase: H[b][n] = relu(sum_k W[n][k]*A[b][k] + C16[cls[b]][n])
// W double-buffered across the 4 n-tiles: 14 loads always in flight.
// ---------------------------------------------------------------------------
__device__ __forceinline__ void do_gemm1(f16* SM, const f16* __restrict__ Wpk,
                                         const f16* __restrict__ C16,
                                         int Ao, int clsr, int wid, int lane,
                                         int ln16, int koct)
{
    half8v afr[14];
    #pragma unroll
    for (int sl = 0; sl < 14; sl++)
        afr[sl] = *(const half8v*)&SM[lad(Ao, ln16, sl * 32 + koct * 8, KS1)];

    const f16* base = Wpk + (long)wid * 4 * 14 * 512 + lane * 8;
    half8v wf[2][14];
    #pragma unroll
    for (int sl = 0; sl < 14; sl++)
        wf[0][sl] = *(const half8v*)&base[sl * 512];

    #pragma unroll
    for (int j = 0; j < 4; j++) {
        if (j < 3) {
            const f16* bn = base + (j + 1) * 14 * 512;
            #pragma unroll
            for (int sl = 0; sl < 14; sl++)
                wf[(j + 1) & 1][sl] = *(const half8v*)&bn[sl * 512];
        }
        fx4 acc = {};
        #pragma unroll
        for (int sl = 0; sl < 14; sl++)
            acc = __builtin_amdgcn_mfma_f32_16x16x32_f16(wf[j & 1][sl], afr[sl], acc, 0, 0, 0);
        int nb = wid * 64 + j * 16 + koct * 4;
        half4v c = *(const half4v*)&C16[clsr * HIDF + nb];
        half4v o;
        #pragma unroll
        for (int r = 0; r < 4; r++)
            o[r] = (f16)fmaxf(acc[r] + (float)c[r], 0.f);
        *(half4v*)&SM[lad(Ho, ln16, nb, HIDF)] = o;
    }
}

// coupling epilogue for one (s,t) quad; scatters y into next-X buffers
__device__ __forceinline__ float couple_store(f16* SM, const float* __restrict__ b2,
        const int* __restrict__ invz, int B1o_, int B2o_, int doScat,
        int Xmo, int Yo, int dbase, int ln16, fx4 sac, fx4 tac)
{
    float jp = 0.f;
    if (dbase + 3 < HALFF) {
        fx4 bs = *(const fx4*)&b2[dbase];
        fx4 bt = *(const fx4*)&b2[dbase + HALFF];
        half4v xv = *(const half4v*)&SM[lad(Xmo, ln16, dbase, KS1)];
        half4v o;
        #pragma unroll
        for (int r = 0; r < 4; r++) {
            float s  = sac[r] + bs[r];
            float tt = tac[r] + bt[r];
            float ls = 0.636f * atanf(s);
            jp += ls;
            o[r] = (f16)(expf(ls) * (float)xv[r] + tt);
        }
        *(half4v*)&SM[lad(Yo, ln16, dbase, KS1)] = o;
        if (doScat) {
            ix4 iv = *(const ix4*)&invz[dbase];
            #pragma unroll
            for (int r = 0; r < 4; r++) {
                int dp = iv[r];
                int dbo = (dp < HALFF) ? B1o_ : B2o_;
                int dk  = (dp < HALFF) ? dp : dp - HALFF;
                SM[lad(dbo, ln16, dk, KS1)] = o[r];
            }
        }
    }
    return jp;
}

// ---------------------------------------------------------------------------
// GEMM2+coupling: 25 (s,t) d-pairs; waves get {wid, wid+8, wid+16},
// wave 0 also pair 24 (clamped rows, invalid quads skipped by couple_store).
// Per pair: 32 W loads issued as one batch; H-frags re-read from LDS per
// slice so ds_reads overlap the W latency.
// ---------------------------------------------------------------------------
__device__ __forceinline__ float do_gemm2(f16* SM, const f16* __restrict__ Wpk,
        const float* __restrict__ b2, const int* __restrict__ invz,
        int B1o_, int B2o_, int doScat, int Xmo, int Yo,
        int wid, int lane, int ln16, int koct)
{
    float jp = 0.f;
    #pragma unroll
    for (int j = 0; j < 4; j++) {
        const int dp = (j < 3) ? (wid + j * 8) : 24;
        const bool act = (j < 3) || (wid == 0);
        if (act) {
            const f16* bp = Wpk + (long)dp * (16 * 2 * 512) + lane * 8;
            half8v ws[16], wt[16];
            #pragma unroll
            for (int sl = 0; sl < 16; sl++)
                ws[sl] = *(const half8v*)&bp[(sl * 2) * 512];
            #pragma unroll
            for (int sl = 0; sl < 16; sl++)
                wt[sl] = *(const half8v*)&bp[(sl * 2 + 1) * 512];
            fx4 sac = {}, tac = {};
            #pragma unroll
            for (int sl = 0; sl < 16; sl++) {
                half8v h = *(const half8v*)&SM[lad(Ho, ln16, sl * 32 + koct * 8, HIDF)];
                sac = __builtin_amdgcn_mfma_f32_16x16x32_f16(ws[sl], h, sac, 0, 0, 0);
                tac = __builtin_amdgcn_mfma_f32_16x16x32_f16(wt[sl], h, tac, 0, 0, 0);
            }
            jp += couple_store(SM, b2, invz, B1o_, B2o_, doScat, Xmo, Yo,
                               dp * 16 + koct * 4, ln16, sac, tac);
        }
    }
    return jp;
}

// ---------------------------------------------------------------------------
// mega kernel: one block = 16 batch rows, entire 20-block cINN in LDS.
// grid 256, block 512 (8 waves).
// ---------------------------------------------------------------------------
__global__ __launch_bounds__(THREADS, 2)
void mega_k(const float* __restrict__ x, const int* __restrict__ lvec,
            const int* __restrict__ invp,
            const f16* __restrict__ Wf1a, const f16* __restrict__ Wf1b,
            const f16* __restrict__ Wf2a, const f16* __restrict__ Wf2b,
            const f16* __restrict__ C16a, const f16* __restrict__ C16b,
            const float* __restrict__ b2a, const float* __restrict__ b2b,
            float* __restrict__ outp)
{
    __shared__ __align__(16) f16 SM[SMH];
    __shared__ float JR[NW][BT];
    const int tid  = threadIdx.x;
    const int wid  = tid >> 6, lane = tid & 63;
    const int ln16 = lane & 15, koct = lane >> 4;
    const int b0g  = blockIdx.x * BT;
    const int clsr = lvec[b0g + ln16];

    int A1 = 0, A2 = 7168, B1 = 14336, B2 = 21504;

    // zero pads (cols [392,448)) of A2, B2, Y1 — stay zero forever
    half8v hz = {};
    for (int idx = tid; idx < 3 * BT * 7; idx += THREADS) {
        int buf = idx / (BT * 7);
        int rem = idx - buf * (BT * 7);
        int b = rem / 7, g = rem - (rem / 7) * 7;
        int base = (buf == 0) ? A2 : (buf == 1) ? B2 : Y1o;
        *(half8v*)&SM[lad(base, b, HALFF + g * 8, KS1)] = hz;
    }
    // initial: X[invp0[q]] = x[b][q]  (coalesced reads, LDS scatter)
    for (int idx = tid; idx < BT * (DF / 4); idx += THREADS) {
        int b = idx / (DF / 4);
        int q = (idx - b * (DF / 4)) * 4;
        fx4 v = *(const fx4*)&x[(long)(b0g + b) * DF + q];
        ix4 iv = *(const ix4*)&invp[q];
        #pragma unroll
        for (int r = 0; r < 4; r++) {
            int dp = iv[r];
            if (dp < HALFF) SM[lad(A1, b, dp, KS1)] = (f16)v[r];
            else            SM[lad(A2, b, dp - HALFF, KS1)] = (f16)v[r];
        }
    }
    __syncthreads();

    float jacc = 0.f;
    #pragma unroll 1
    for (int i = 0; i < NBLK; i++) {
        const int* ivz = invp + (long)((i + 1 < NBLK) ? (i + 1) : 0) * DF;
        const int doScat = (i + 1 < NBLK);
        // substep 2: H = relu(X2@W1 + cond); (s,t) = H@W2; Y1 = exp(ls)*X1 + t
        do_gemm1(SM, Wf1a + (long)i * 32 * 14 * 512, C16a + (long)i * 10 * HIDF,
                 A2, clsr, wid, lane, ln16, koct);
        __syncthreads();
        jacc += do_gemm2(SM, Wf2a + (long)i * 25 * 16 * 2 * 512, b2a + (long)i * DF,
                         ivz, B1, B2, doScat, A1, Y1o, wid, lane, ln16, koct);
        __syncthreads();
        // substep 1: H = relu(Y1@W1 + cond); Y2 = exp(ls)*X2 + t
        do_gemm1(SM, Wf1b + (long)i * 32 * 14 * 512, C16b + (long)i * 10 * HIDF,
                 Y1o, clsr, wid, lane, ln16, koct);
        __syncthreads();
        jacc += do_gemm2(SM, Wf2b + (long)i * 25 * 16 * 2 * 512, b2b + (long)i * DF,
                         ivz + HALFF, B1, B2, doScat, A2, Y2o, wid, lane, ln16, koct);
        __syncthreads();
        int t1 = A1; A1 = B1; B1 = t1;
        int t2 = A2; A2 = B2; B2 = t2;
    }

    // output z = concat(Y1, Y2) in fp32
    for (int idx = tid; idx < BT * (DF / 4); idx += THREADS) {
        int b = idx / (DF / 4);
        int q = (idx - b * (DF / 4)) * 4;
        int so = (q < HALFF) ? Y1o : Y2o;
        int kk = (q < HALFF) ? q : q - HALFF;
        half4v v = *(const half4v*)&SM[lad(so, b, kk, KS1)];
        fx4 o;
        #pragma unroll
        for (int r = 0; r < 4; r++) o[r] = (float)v[r];
        *(fx4*)&outp[(long)(b0g + b) * DF + q] = o;
    }
    // jac reduce
    float j1 = jacc + __shfl_xor(jacc, 16);
    j1 += __shfl_xor(j1, 32);
    if (koct == 0) JR[wid][ln16] = j1;
    __syncthreads();
    if (tid < BT) {
        float s = 0.f;
        #pragma unroll
        for (int w = 0; w < NW; w++) s += JR[w][tid];
        outp[(long)BN * DF + b0g + tid] = s;
    }
}

// ---------------------------------------------------------------------------
extern "C" void kernel_launch(void* const* d_in, const int* in_sizes, int n_in,
                              void* d_out, int out_size, void* d_ws, size_t ws_size,
                              hipStream_t stream)
{
    const float* x     = (const float*)d_in[0];
    const int*   l     = (const int*)d_in[1];
    const int*   perms = (const int*)d_in[2];
    const float* s1W1  = (const float*)d_in[3];
    const float* s1b1  = (const float*)d_in[4];
    const float* s1W2  = (const float*)d_in[5];
    const float* s1b2  = (const float*)d_in[6];
    const float* s2W1  = (const float*)d_in[7];
    const float* s2b1  = (const float*)d_in[8];
    const float* s2W2  = (const float*)d_in[9];
    const float* s2b2  = (const float*)d_in[10];
    float* out = (float*)d_out;

    const long W1E = 32L * 14 * 512;       // halves per packed W1 matrix
    const long W2E = 25L * 16 * 2 * 512;   // halves per packed W2 matrix
    f16* Wf1a = (f16*)d_ws;
    f16* Wf1b = Wf1a + W1E * NBLK;
    f16* Wf2a = Wf1b + W1E * NBLK;
    f16* Wf2b = Wf2a + W2E * NBLK;
    f16* C16a = Wf2b + W2E * NBLK;
    f16* C16b = C16a + (long)NBLK * 10 * HIDF;
    int* invp = (int*)(C16b + (long)NBLK * 10 * HIDF);

    pack1_k<<<dim3(32 * 14, NBLK), 64, 0, stream>>>(s2W1, Wf1a);
    pack1_k<<<dim3(32 * 14, NBLK), 64, 0, stream>>>(s1W1, Wf1b);
    pack2_k<<<dim3(25 * 16, NBLK), 128, 0, stream>>>(s2W2, Wf2a);
    pack2_k<<<dim3(25 * 16, NBLK), 128, 0, stream>>>(s1W2, Wf2b);
    prep_c16_k<<<NBLK, 256, 0, stream>>>(s2W1, s2b1, C16a);
    prep_c16_k<<<NBLK, 256, 0, stream>>>(s1W1, s1b1, C16b);
    inv_k<<<NBLK, 256, 0, stream>>>(perms, invp);

    mega_k<<<BN / BT, THREADS, 0, stream>>>(x, l, invp,
            Wf1a, Wf1b, Wf2a, Wf2b, C16a, C16b, s2b2, s1b2, out);
}

// Round 8
// 761.285 us; speedup vs baseline: 2.7492x; 1.1048x over previous
//
#include <hip/hip_runtime.h>

#define BN 4096
#define DF 784
#define HALFF 392
#define HIDF 512
#define NBLK 20
#define NSL1 13      // K-slices gemm1 (416 = 13*32; real K = 392, zero-padded)
#define NSL2 16      // K-slices gemm2 (512)
#define XP  448      // X-buffer LDS pitch (halves)
#define BT 16        // batch rows per block
#define NW 16        // waves per block
#define THREADS 1024

// LDS half-offsets: A1, A2, B1, B2 (pitch XP), H (pitch HIDF)
#define A1o 0
#define A2o 7168
#define B1o 14336
#define B2o 21504
#define Ho  28672
#define SMH 36864    // 73,728 B

typedef _Float16 f16;
typedef _Float16 half4v __attribute__((ext_vector_type(4)));
typedef _Float16 half8v __attribute__((ext_vector_type(8)));
typedef float    fx4    __attribute__((ext_vector_type(4)));
typedef int      ix4    __attribute__((ext_vector_type(4)));

// swizzled LDS index (halves): 8-half chunks XOR'd by row&7 within 64-half groups
__device__ __forceinline__ int lad(int base, int b, int k, int pitch)
{
    return base + b * pitch + (k & ~63) + ((((k >> 3) & 7) ^ (b & 7)) << 3) + (k & 7);
}

// ---------------------------------------------------------------------------
// pack1_k: W1 fp32 [m][402][512] -> fragment-major fp16
//   Wpk1[m][ntile=32][sl=13][lane=64][8], lane l -> row n = ntile*16+(l&15),
//   k = sl*32+(l>>4)*8+e, zero for k >= 392.  grid (32*13, 20), block 64.
// ---------------------------------------------------------------------------
__global__ void pack1_k(const float* __restrict__ W1, f16* __restrict__ dst)
{
    const int m = blockIdx.y;
    const int nt = blockIdx.x / NSL1, sl = blockIdx.x % NSL1;
    const int l = threadIdx.x;
    const int n = nt * 16 + (l & 15);
    const int kb = sl * 32 + (l >> 4) * 8;
    const float* src = W1 + (long)m * 402 * 512;
    half8v o;
    #pragma unroll
    for (int e = 0; e < 8; e++) {
        int k = kb + e;
        o[e] = (k < HALFF) ? (f16)src[(long)k * 512 + n] : (f16)0.f;
    }
    *(half8v*)&dst[(((long)(m * 32 + nt) * NSL1) + sl) * 512 + l * 8] = o;
}

// ---------------------------------------------------------------------------
// pack2_k: W2 fp32 [m][512][784] -> Wpk2[m][dt=25][sl=16][c=2][lane][8]
//   c=0: s-row d=min(dt*16+(l&15),391); c=1: t-row d+392.
//   grid (400, 20), block 128.
// ---------------------------------------------------------------------------
__global__ void pack2_k(const float* __restrict__ W2, f16* __restrict__ dst)
{
    const int m = blockIdx.y;
    const int dt = blockIdx.x / 16, sl = blockIdx.x % 16;
    const int c = threadIdx.x >> 6, l = threadIdx.x & 63;
    int dr = dt * 16 + (l & 15);
    if (dr >= HALFF) dr = HALFF - 1;
    const int d = dr + c * HALFF;
    const int kb = sl * 32 + (l >> 4) * 8;
    const float* src = W2 + (long)m * 512 * 784;
    half8v o;
    #pragma unroll
    for (int e = 0; e < 8; e++)
        o[e] = (f16)src[(long)(kb + e) * 784 + d];
    *(half8v*)&dst[((((long)(m * 25 + dt) * 16) + sl) * 2 + c) * 512 + l * 8] = o;
}

// c16[m][cls][n] = W1[m][392+cls][n] + b1[m][n]  (bias folded), fp16
__global__ void prep_c16_k(const float* __restrict__ W1, const float* __restrict__ b1,
                           f16* __restrict__ dst)
{
    const int m = blockIdx.x;
    for (int idx = threadIdx.x; idx < 10 * HIDF; idx += 256) {
        int cls = idx >> 9, n = idx & 511;
        dst[(long)m * 10 * HIDF + idx] =
            (f16)(W1[(long)m * 402 * 512 + (long)(HALFF + cls) * 512 + n] + b1[(long)m * HIDF + n]);
    }
}

__global__ void inv_k(const int* __restrict__ perms, int* __restrict__ invp)
{
    const int i = blockIdx.x;
    for (int d = threadIdx.x; d < DF; d += 256) {
        int src = perms[(long)i * DF + d];
        invp[(long)i * DF + src] = d;
    }
}

// ---------------------------------------------------------------------------
// GEMM1 phase: H[b][n] = relu(sum_k W[n][k]*A[b][k] + C16[cls[b]][n])
// 16 waves x 2 n-tiles each. A-frags re-read from LDS per tile (VGPR diet).
// ---------------------------------------------------------------------------
__device__ __forceinline__ void do_gemm1(f16* SM, const f16* __restrict__ Wpk,
                                         const f16* __restrict__ C16,
                                         int Ao, int clsr, int wid, int lane,
                                         int ln16, int koct)
{
    #pragma unroll
    for (int j = 0; j < 2; j++) {
        const int tile = wid * 2 + j;
        const f16* bp = Wpk + ((long)tile * NSL1) * 512 + lane * 8;
        half8v wf[NSL1];
        #pragma unroll
        for (int sl = 0; sl < NSL1; sl++)
            wf[sl] = *(const half8v*)&bp[sl * 512];
        fx4 acc = {};
        #pragma unroll
        for (int sl = 0; sl < NSL1; sl++) {
            half8v a = *(const half8v*)&SM[lad(Ao, ln16, sl * 32 + koct * 8, XP)];
            acc = __builtin_amdgcn_mfma_f32_16x16x32_f16(wf[sl], a, acc, 0, 0, 0);
        }
        const int nb = tile * 16 + koct * 4;
        half4v c = *(const half4v*)&C16[clsr * HIDF + nb];
        half4v o;
        #pragma unroll
        for (int r = 0; r < 4; r++)
            o[r] = (f16)fmaxf(acc[r] + (float)c[r], 0.f);
        *(half4v*)&SM[lad(Ho, ln16, nb, HIDF)] = o;
    }
}

// coupling epilogue for one (s,t) quad: y overwrites x IN PLACE (x is dead
// after its read; each thread owns its quad) + scatter into next-X buffers.
__device__ __forceinline__ float couple_store(f16* SM, const float* __restrict__ b2,
        const int* __restrict__ ivz, int B1_, int B2_, int doScat,
        int Xmo, int dbase, int ln16, fx4 sac, fx4 tac)
{
    float jp = 0.f;
    if (dbase + 3 < HALFF) {
        fx4 bs = *(const fx4*)&b2[dbase];
        fx4 bt = *(const fx4*)&b2[dbase + HALFF];
        const int xa = lad(Xmo, ln16, dbase, XP);
        half4v xv = *(const half4v*)&SM[xa];
        half4v o;
        #pragma unroll
        for (int r = 0; r < 4; r++) {
            float s  = sac[r] + bs[r];
            float tt = tac[r] + bt[r];
            float ls = 0.636f * atanf(s);
            jp += ls;
            o[r] = (f16)(expf(ls) * (float)xv[r] + tt);
        }
        *(half4v*)&SM[xa] = o;          // y in place of x
        if (doScat) {
            ix4 iv = *(const ix4*)&ivz[dbase];
            #pragma unroll
            for (int r = 0; r < 4; r++) {
                int dp = iv[r];
                int dbo = (dp < HALFF) ? B1_ : B2_;
                int dk  = (dp < HALFF) ? dp : dp - HALFF;
                SM[lad(dbo, ln16, dk, XP)] = o[r];
            }
        }
    }
    return jp;
}

// ---------------------------------------------------------------------------
// GEMM2+coupling: 25 (s,t) d-pairs over 16 waves: pairs {wid} and {wid+16}.
// s-chain then t-chain per pair (one 16-frag W buffer = 64 VGPR).
// ---------------------------------------------------------------------------
__device__ __forceinline__ float do_gemm2(f16* SM, const f16* __restrict__ Wpk,
        const float* __restrict__ b2, const int* __restrict__ ivz,
        int B1_, int B2_, int doScat, int Xmo,
        int wid, int lane, int ln16, int koct)
{
    float jp = 0.f;
    #pragma unroll
    for (int rnd = 0; rnd < 2; rnd++) {
        const int dp = wid + rnd * 16;
        if (dp < 25) {
            const f16* bp = Wpk + (long)dp * (NSL2 * 2 * 512) + lane * 8;
            fx4 sac = {}, tac = {};
            {
                half8v w[NSL2];
                #pragma unroll
                for (int sl = 0; sl < NSL2; sl++)
                    w[sl] = *(const half8v*)&bp[(sl * 2) * 512];
                #pragma unroll
                for (int sl = 0; sl < NSL2; sl++) {
                    half8v h = *(const half8v*)&SM[lad(Ho, ln16, sl * 32 + koct * 8, HIDF)];
                    sac = __builtin_amdgcn_mfma_f32_16x16x32_f16(w[sl], h, sac, 0, 0, 0);
                }
            }
            {
                half8v w[NSL2];
                #pragma unroll
                for (int sl = 0; sl < NSL2; sl++)
                    w[sl] = *(const half8v*)&bp[(sl * 2 + 1) * 512];
                #pragma unroll
                for (int sl = 0; sl < NSL2; sl++) {
                    half8v h = *(const half8v*)&SM[lad(Ho, ln16, sl * 32 + koct * 8, HIDF)];
                    tac = __builtin_amdgcn_mfma_f32_16x16x32_f16(w[sl], h, tac, 0, 0, 0);
                }
            }
            jp += couple_store(SM, b2, ivz, B1_, B2_, doScat, Xmo,
                               dp * 16 + koct * 4, ln16, sac, tac);
        }
    }
    return jp;
}

// ---------------------------------------------------------------------------
// mega kernel: one block = 16 batch rows, entire 20-block cINN in LDS.
// grid 256, block 1024 (16 waves, 4/SIMD).
// ---------------------------------------------------------------------------
__global__ __launch_bounds__(THREADS, 4)
void mega_k(const float* __restrict__ x, const int* __restrict__ lvec,
            const int* __restrict__ invp,
            const f16* __restrict__ Wf1a, const f16* __restrict__ Wf1b,
            const f16* __restrict__ Wf2a, const f16* __restrict__ Wf2b,
            const f16* __restrict__ C16a, const f16* __restrict__ C16b,
            const float* __restrict__ b2a, const float* __restrict__ b2b,
            float* __restrict__ outp)
{
    __shared__ __align__(16) f16 SM[SMH];
    __shared__ float JR[NW][BT];
    const int tid  = threadIdx.x;
    const int wid  = tid >> 6, lane = tid & 63;
    const int ln16 = lane & 15, koct = lane >> 4;
    const int b0g  = blockIdx.x * BT;
    const int clsr = lvec[b0g + ln16];

    int A1 = A1o, A2 = A2o, B1 = B1o, B2 = B2o;

    // zero pads (cols [392,448)) of all four X-buffers — stay zero forever
    half8v hz = {};
    for (int idx = tid; idx < 4 * BT * 7; idx += THREADS) {
        int buf = idx / (BT * 7);
        int rem = idx - buf * (BT * 7);
        int b = rem / 7, g = rem - (rem / 7) * 7;
        *(half8v*)&SM[lad(buf * 7168, b, HALFF + g * 8, XP)] = hz;
    }
    // initial: X[invp0[q]] = x[b][q]  (coalesced reads, LDS scatter)
    for (int idx = tid; idx < BT * (DF / 4); idx += THREADS) {
        int b = idx / (DF / 4);
        int q = (idx - b * (DF / 4)) * 4;
        fx4 v = *(const fx4*)&x[(long)(b0g + b) * DF + q];
        ix4 iv = *(const ix4*)&invp[q];
        #pragma unroll
        for (int r = 0; r < 4; r++) {
            int dp = iv[r];
            if (dp < HALFF) SM[lad(A1, b, dp, XP)] = (f16)v[r];
            else            SM[lad(A2, b, dp - HALFF, XP)] = (f16)v[r];
        }
    }
    __syncthreads();

    float jacc = 0.f;
    #pragma unroll 1
    for (int i = 0; i < NBLK; i++) {
        const int* ivz = invp + (long)((i + 1 < NBLK) ? (i + 1) : 0) * DF;
        const int doScat = (i + 1 < NBLK);
        // substep 2: H = relu(X2@W1 + cond); (s,t) = H@W2; X1 <- exp(ls)*X1 + t
        do_gemm1(SM, Wf1a + (long)i * 32 * NSL1 * 512, C16a + (long)i * 10 * HIDF,
                 A2, clsr, wid, lane, ln16, koct);
        __syncthreads();
        jacc += do_gemm2(SM, Wf2a + (long)i * 25 * NSL2 * 2 * 512, b2a + (long)i * DF,
                         ivz, B1, B2, doScat, A1, wid, lane, ln16, koct);
        __syncthreads();
        // substep 1: H = relu(Y1@W1 + cond); X2 <- exp(ls)*X2 + t
        do_gemm1(SM, Wf1b + (long)i * 32 * NSL1 * 512, C16b + (long)i * 10 * HIDF,
                 A1, clsr, wid, lane, ln16, koct);
        __syncthreads();
        jacc += do_gemm2(SM, Wf2b + (long)i * 25 * NSL2 * 2 * 512, b2b + (long)i * DF,
                         ivz + HALFF, B1, B2, doScat, A2, wid, lane, ln16, koct);
        __syncthreads();
        if (i + 1 < NBLK) {
            int t1 = A1; A1 = B1; B1 = t1;
            int t2 = A2; A2 = B2; B2 = t2;
        }
    }

    // output z = concat(y1, y2) = (A1, A2) in fp32
    for (int idx = tid; idx < BT * (DF / 4); idx += THREADS) {
        int b = idx / (DF / 4);
        int q = (idx - b * (DF / 4)) * 4;
        int so = (q < HALFF) ? A1 : A2;
        int kk = (q < HALFF) ? q : q - HALFF;
        half4v v = *(const half4v*)&SM[lad(so, b, kk, XP)];
        fx4 o;
        #pragma unroll
        for (int r = 0; r < 4; r++) o[r] = (float)v[r];
        *(fx4*)&outp[(long)(b0g + b) * DF + q] = o;
    }
    // jac reduce
    float j1 = jacc + __shfl_xor(jacc, 16);
    j1 += __shfl_xor(j1, 32);
    if (koct == 0) JR[wid][ln16] = j1;
    __syncthreads();
    if (tid < BT) {
        float s = 0.f;
        #pragma unroll
        for (int w = 0; w < NW; w++) s += JR[w][tid];
        outp[(long)BN * DF + b0g + tid] = s;
    }
}

// ---------------------------------------------------------------------------
extern "C" void kernel_launch(void* const* d_in, const int* in_sizes, int n_in,
                              void* d_out, int out_size, void* d_ws, size_t ws_size,
                              hipStream_t stream)
{
    const float* x     = (const float*)d_in[0];
    const int*   l     = (const int*)d_in[1];
    const int*   perms = (const int*)d_in[2];
    const float* s1W1  = (const float*)d_in[3];
    const float* s1b1  = (const float*)d_in[4];
    const float* s1W2  = (const float*)d_in[5];
    const float* s1b2  = (const float*)d_in[6];
    const float* s2W1  = (const float*)d_in[7];
    const float* s2b1  = (const float*)d_in[8];
    const float* s2W2  = (const float*)d_in[9];
    const float* s2b2  = (const float*)d_in[10];
    float* out = (float*)d_out;

    const long W1E = 32L * NSL1 * 512;       // halves per packed W1 matrix
    const long W2E = 25L * NSL2 * 2 * 512;   // halves per packed W2 matrix
    f16* Wf1a = (f16*)d_ws;
    f16* Wf1b = Wf1a + W1E * NBLK;
    f16* Wf2a = Wf1b + W1E * NBLK;
    f16* Wf2b = Wf2a + W2E * NBLK;
    f16* C16a = Wf2b + W2E * NBLK;
    f16* C16b = C16a + (long)NBLK * 10 * HIDF;
    int* invp = (int*)(C16b + (long)NBLK * 10 * HIDF);

    pack1_k<<<dim3(32 * NSL1, NBLK), 64, 0, stream>>>(s2W1, Wf1a);
    pack1_k<<<dim3(32 * NSL1, NBLK), 64, 0, stream>>>(s1W1, Wf1b);
    pack2_k<<<dim3(25 * 16, NBLK), 128, 0, stream>>>(s2W2, Wf2a);
    pack2_k<<<dim3(25 * 16, NBLK), 128, 0, stream>>>(s1W2, Wf2b);
    prep_c16_k<<<NBLK, 256, 0, stream>>>(s2W1, s2b1, C16a);
    prep_c16_k<<<NBLK, 256, 0, stream>>>(s1W1, s1b1, C16b);
    inv_k<<<NBLK, 256, 0, stream>>>(perms, invp);

    mega_k<<<BN / BT, THREADS, 0, stream>>>(x, l, invp,
            Wf1a, Wf1b, Wf2a, Wf2b, C16a, C16b, s2b2, s1b2, out);
}